// Round 11
// baseline (210.726 us; speedup 1.0000x reference)
//
#include <hip/hip_runtime.h>
#include <hip/hip_bf16.h>

// ---------------------------------------------------------------------------
// ShuffleRowAttention: B=16, N=1024, DIM=768, H=12, DH=64. fp32 in/out
// (runtime-detected). Round 17:
//  * R16 post-mortem: grid swap HURT (FETCH 72.7->144.7 MB, gemm<0> +2 us).
//    M-fast default order (one A pass, L3-resident B) was already optimal.
//    Reverted to R15 identity mapping. GEMM schedule surgery closed: five
//    variants (R8-R15) all land at 28-29% MfmaUtil -> 128^2/K=768 shape
//    ceiling (~690 TF); no pipe saturated, LDS/HBM rooflines far above.
//  * attn: Ps pad 88 -> 68 cols (stride 136 B -> bank-stride 2 -> <=2-way
//    conflicts, free per m136). LDS 55296 -> 50176 B crosses the 3-blocks/CU
//    boundary (53333): occupancy 2 -> 3 blocks/CU (+50% waves to hide the
//    per-kt vmcnt(0) drain), grid 1536 = exactly 2 full dispatch rounds.
//    __launch_bounds__(256,3) (budget 170 VGPR, kernel ~90).
//  * prep fusion kept (R16). GEMM inner loop unchanged (R15 triple-buffer,
//    counted vmcnt(4)+lgkmcnt(0) WAR fence, Vt fused into gemm<0>).
// ---------------------------------------------------------------------------

typedef __bf16 bf16x8 __attribute__((ext_vector_type(8)));
typedef __bf16 bf16x4 __attribute__((ext_vector_type(4)));
typedef float  f32x4  __attribute__((ext_vector_type(4)));

__device__ __forceinline__ f32x4 mfma16(bf16x8 a, bf16x8 b, f32x4 c) {
    return __builtin_amdgcn_mfma_f32_16x16x32_bf16(a, b, c, 0, 0, 0);
}

// async 16B/lane global->LDS: lds base wave-uniform; lane i deposits at +16*i.
__device__ __forceinline__ void async16(const void* g, void* l) {
    __builtin_amdgcn_global_load_lds(
        (const __attribute__((address_space(1))) unsigned int*)g,
        (__attribute__((address_space(3))) unsigned int*)l,
        16, 0, 0);
}

// ---------------------------------------------------------------------------
// Fused prep: dtype-detect (per block, from its own source) + X fp32->bf16
// convert + Wqkv/Wout transpose. Blocks [0,1024): convert X; [1024,1456):
// transpose Wqkv (768x2304); [1456,1600): transpose Wout (768x768).
// Detector: fp32 data viewed as uint16 halves -> ~25% of low halves have
// exponent-field >= 0xC0 (mantissa bits ~uniform); true bf16 N(0,sigma)
// never does. Scale-invariant -> valid per-source. Block 0 publishes flag.
// ---------------------------------------------------------------------------
__global__ __launch_bounds__(256)
void prep(const void* __restrict__ x, __bf16* __restrict__ Xc,
          const void* __restrict__ Wqkv, __bf16* __restrict__ Wqt,
          const void* __restrict__ Wout, __bf16* __restrict__ Wot,
          int* __restrict__ flag) {
    __shared__ __bf16 tile[64][65];
    __shared__ int cnt;
    const int bid = blockIdx.x;
    const int tid = threadIdx.x;

    const unsigned short* raw =
        (bid < 1024) ? (const unsigned short*)x
                     : (bid < 1456) ? (const unsigned short*)Wqkv
                                    : (const unsigned short*)Wout;
    if (tid == 0) cnt = 0;
    __syncthreads();
    int local = 0;
    for (int i = tid; i < 2048; i += 256) {
        unsigned e = (raw[i] >> 7) & 0xFFu;
        if (e >= 0xC0u) local++;
    }
    atomicAdd(&cnt, local);
    __syncthreads();
    const int f = (cnt > 16) ? 1 : 0;
    if (bid == 0 && tid == 0) *flag = f;

    if (bid < 1024) {
        // ---- convert X: grid-stride over 16384*768/4 float4-groups ----
        const int n4 = 16384 * 768 / 4;
        int i = bid * 256 + tid;
        const int stride = 1024 * 256;
        if (f) {
            const float4* s = (const float4*)x;
            for (; i < n4; i += stride) {
                float4 v = s[i];
                bf16x4 o;
                o[0] = (__bf16)v.x; o[1] = (__bf16)v.y;
                o[2] = (__bf16)v.z; o[3] = (__bf16)v.w;
                *(bf16x4*)&Xc[(size_t)i * 4] = o;
            }
        } else {
            const ushort4* s = (const ushort4*)x;
            for (; i < n4; i += stride) *(ushort4*)&Xc[(size_t)i * 4] = s[i];
        }
    } else {
        // ---- transpose W (64x64 tile via LDS) ----
        const void* in;
        __bf16* out;
        int R, C, c0, r0;
        if (bid < 1456) {
            int t = bid - 1024;           // 36 x 12 tiles
            in = Wqkv; out = Wqt; R = 768; C = 2304;
            c0 = (t % 36) * 64; r0 = (t / 36) * 64;
        } else {
            int t = bid - 1456;           // 12 x 12 tiles
            in = Wout; out = Wot; R = 768; C = 768;
            c0 = (t % 12) * 64; r0 = (t / 12) * 64;
        }
        const int tx = tid & 63, ty = tid >> 6;
#pragma unroll
        for (int k = 0; k < 16; ++k) {
            int r = ty + 4 * k;
            size_t idx = (size_t)(r0 + r) * C + c0 + tx;
            tile[r][tx] = f ? (__bf16)((const float*)in)[idx] : ((const __bf16*)in)[idx];
        }
        __syncthreads();
#pragma unroll
        for (int k = 0; k < 16; ++k) {
            int cc = ty + 4 * k;
            out[(size_t)(c0 + cc) * R + r0 + tx] = tile[tx][cc];
        }
    }
}

// ---------------------------------------------------------------------------
// GEMM: C[M x N] = A[M x K] * Bt[N x K]^T (+ bias); bf16 in, fp32 acc.
// 128x128 tile, BK=32, 4 waves, 16x16x32 MFMA. R15/R17 structure:
//  - LDS TRIPLE buffer: buf b at smem + b*16384 { A[128x32] @ +0, B @ +8192 }.
//    16B-chunk slot s of row r holds global chunk s^((r>>1)&3) (XOR swizzle,
//    conflict-free ds_read_b128; staged via pre-swizzled global col).
//  - Tile kt: { s_waitcnt vmcnt(4) lgkmcnt(0); s_barrier; stage(kt+2) ->
//    buf (kt+2)%3; 8x ds_read_b128 + 16 MFMA on buf kt%3 }.
//  - Identity tile mapping, M-fast dispatch (R16 swap hurt: FETCH 2x).
//  - nkt = K/32 must be 24 (K=768): 7 literal groups of 3 + 3-tile tail.
// MODE 0: C bf16, no bias; V-range blocks (bn>=1536) write transposed to vt
//         instead of Cout (QKV V cols are dead -- O overwrites them).
// MODE 1: C/bias dtype per flag.
// ---------------------------------------------------------------------------
#define GMFMA16()                                                       \
    acc[0][0] = mfma16(af0, bf0, acc[0][0]);                            \
    acc[0][1] = mfma16(af0, bf1, acc[0][1]);                            \
    acc[0][2] = mfma16(af0, bf2, acc[0][2]);                            \
    acc[0][3] = mfma16(af0, bf3, acc[0][3]);                            \
    acc[1][0] = mfma16(af1, bf0, acc[1][0]);                            \
    acc[1][1] = mfma16(af1, bf1, acc[1][1]);                            \
    acc[1][2] = mfma16(af1, bf2, acc[1][2]);                            \
    acc[1][3] = mfma16(af1, bf3, acc[1][3]);                            \
    acc[2][0] = mfma16(af2, bf0, acc[2][0]);                            \
    acc[2][1] = mfma16(af2, bf1, acc[2][1]);                            \
    acc[2][2] = mfma16(af2, bf2, acc[2][2]);                            \
    acc[2][3] = mfma16(af2, bf3, acc[2][3]);                            \
    acc[3][0] = mfma16(af3, bf0, acc[3][0]);                            \
    acc[3][1] = mfma16(af3, bf1, acc[3][1]);                            \
    acc[3][2] = mfma16(af3, bf2, acc[3][2]);                            \
    acc[3][3] = mfma16(af3, bf3, acc[3][3])

// Tile step. RD/ST: literal byte offsets of read/stage buffers.
// VMK: 4 -> vmcnt(4), 0 -> vmcnt(0). Wait at TOP pins prior ds_reads
// complete (lgkmcnt) AND tile kt's staging landed (vmcnt), then barrier,
// then stage, then compute.
#define GTILE(RD, ST, DO_STAGE, VMK) do {                               \
    if ((VMK) == 4)                                                     \
        asm volatile("s_waitcnt vmcnt(4) lgkmcnt(0)" ::: "memory");     \
    else                                                                \
        asm volatile("s_waitcnt vmcnt(0) lgkmcnt(0)" ::: "memory");     \
    __builtin_amdgcn_s_barrier();                                       \
    if (DO_STAGE) {                                                     \
        async16(gA0, smem + (ST) + stA0);                               \
        async16(gA1, smem + (ST) + stA1);                               \
        async16(gB0, smem + (ST) + 8192 + stA0);                        \
        async16(gB1, smem + (ST) + 8192 + stA1);                        \
        gA0 += 32; gA1 += 32; gB0 += 32; gB1 += 32;                     \
    }                                                                   \
    bf16x8 af0 = *(const bf16x8*)(smem + (RD) + aoff0);                 \
    bf16x8 af1 = *(const bf16x8*)(smem + (RD) + aoff1);                 \
    bf16x8 af2 = *(const bf16x8*)(smem + (RD) + aoff2);                 \
    bf16x8 af3 = *(const bf16x8*)(smem + (RD) + aoff3);                 \
    bf16x8 bf0 = *(const bf16x8*)(smem + (RD) + boff0);                 \
    bf16x8 bf1 = *(const bf16x8*)(smem + (RD) + boff1);                 \
    bf16x8 bf2 = *(const bf16x8*)(smem + (RD) + boff2);                 \
    bf16x8 bf3 = *(const bf16x8*)(smem + (RD) + boff3);                 \
    GMFMA16();                                                          \
} while (0)

template <int MODE>
__global__ __launch_bounds__(256, 3)
void gemm_bt(const __bf16* __restrict__ A, int lda,
             const __bf16* __restrict__ Bt,
             const void* __restrict__ bias,
             void* __restrict__ Cout, int ldc,
             int K, const int* __restrict__ flag,
             __bf16* __restrict__ vt) {
    __shared__ __align__(16) char smem[49152];
    const int tid  = threadIdx.x;
    const int wid  = tid >> 6;
    const int lane = tid & 63;
    const int quad = lane >> 4;
    const int l15  = lane & 15;

    // identity tile mapping, M-fast (R16 swap reverted)
    const int bm = blockIdx.x * 128;
    const int bn = blockIdx.y * 128;

    const int wm = (wid & 1) * 64;
    const int wn = (wid >> 1) * 64;
    const int srow  = lane >> 2;
    const int sslot = lane & 3;

    // held staging pointers (global chunk pre-swizzled: slot s <- chunk
    // s^((r>>1)&3), deposited linearly at LDS slot sslot)
    const int rA0 = wid * 16 + srow;
    const int rA1 = 64 + wid * 16 + srow;
    const __bf16* gA0 = A  + (size_t)(bm + rA0) * lda + ((sslot ^ ((rA0 >> 1) & 3)) << 3);
    const __bf16* gA1 = A  + (size_t)(bm + rA1) * lda + ((sslot ^ ((rA1 >> 1) & 3)) << 3);
    const __bf16* gB0 = Bt + (size_t)(bn + rA0) * K   + ((sslot ^ ((rA0 >> 1) & 3)) << 3);
    const __bf16* gB1 = Bt + (size_t)(bn + rA1) * K   + ((sslot ^ ((rA1 >> 1) & 3)) << 3);
    const int stA0 = (wid * 16) * 64;        // + lane*16 implicit (bytes)
    const int stA1 = (64 + wid * 16) * 64;

    // frag read byte offsets (loop-invariant; buffer base is a literal)
    const int rf0 = wm + 0 * 16 + l15, rf1 = wm + 1 * 16 + l15;
    const int rf2 = wm + 2 * 16 + l15, rf3 = wm + 3 * 16 + l15;
    const int aoff0 = rf0 * 64 + ((quad ^ ((rf0 >> 1) & 3)) * 16);
    const int aoff1 = rf1 * 64 + ((quad ^ ((rf1 >> 1) & 3)) * 16);
    const int aoff2 = rf2 * 64 + ((quad ^ ((rf2 >> 1) & 3)) * 16);
    const int aoff3 = rf3 * 64 + ((quad ^ ((rf3 >> 1) & 3)) * 16);
    const int rg0 = wn + 0 * 16 + l15, rg1 = wn + 1 * 16 + l15;
    const int rg2 = wn + 2 * 16 + l15, rg3 = wn + 3 * 16 + l15;
    const int boff0 = 8192 + rg0 * 64 + ((quad ^ ((rg0 >> 1) & 3)) * 16);
    const int boff1 = 8192 + rg1 * 64 + ((quad ^ ((rg1 >> 1) & 3)) * 16);
    const int boff2 = 8192 + rg2 * 64 + ((quad ^ ((rg2 >> 1) & 3)) * 16);
    const int boff3 = 8192 + rg3 * 64 + ((quad ^ ((rg3 >> 1) & 3)) * 16);

    f32x4 acc[4][4];
#pragma unroll
    for (int i = 0; i < 4; ++i)
#pragma unroll
        for (int j = 0; j < 4; ++j) acc[i][j] = (f32x4)0.0f;

    // ---- prologue: stage tile 0 -> buf0, tile 1 -> buf1 (8 loads in flight).
    async16(gA0, smem + stA0);
    async16(gA1, smem + stA1);
    async16(gB0, smem + 8192 + stA0);
    async16(gB1, smem + 8192 + stA1);
    gA0 += 32; gA1 += 32; gB0 += 32; gB1 += 32;
    async16(gA0, smem + 16384 + stA0);
    async16(gA1, smem + 16384 + stA1);
    async16(gB0, smem + 16384 + 8192 + stA0);
    async16(gB1, smem + 16384 + 8192 + stA1);
    gA0 += 32; gA1 += 32; gB0 += 32; gB1 += 32;

    // ---- main loop: nkt = 24 tiles = 7 literal groups of 3 + 3-tile tail ----
#pragma unroll 1
    for (int g = 0; g < 7; ++g) {
        GTILE(0,     32768, true, 4);   // tile 3g+0: read buf0, stage -> buf2
        GTILE(16384, 0,     true, 4);   // tile 3g+1: read buf1, stage -> buf0
        GTILE(32768, 16384, true, 4);   // tile 3g+2: read buf2, stage -> buf1
    }
    GTILE(0,     32768, true,  4);      // tile 21: stages tile 23 -> buf2
    GTILE(16384, 0,     false, 4);      // tile 22
    GTILE(32768, 0,     false, 0);      // tile 23: final drain

    // ---- MODE 0 V-range blocks: write acc transposed to Vt, skip Cout ----
    if (MODE == 0 && bn >= 1536) {
        const int bq = bm >> 10;                         // batch index
        const int n0 = (bm & 1023) + wm + quad * 4;      // n base for this lane
        const int colb = bn - 1536 + wn;                 // V feature base
        // vt row = (b*12 + col/64)*64 + col%64 = b*768 + col
#pragma unroll
        for (int mi = 0; mi < 4; ++mi)
#pragma unroll
            for (int ni = 0; ni < 4; ++ni) {
                int col = colb + ni * 16 + l15;
                bf16x4 v;
                v[0] = (__bf16)acc[mi][ni][0];
                v[1] = (__bf16)acc[mi][ni][1];
                v[2] = (__bf16)acc[mi][ni][2];
                v[3] = (__bf16)acc[mi][ni][3];
                *(bf16x4*)&vt[((size_t)bq * 768 + col) * 1024 + n0 + mi * 16] = v;
            }
        return;   // block-uniform branch; no barriers skipped asymmetrically
    }

    // ---- epilogue: bias add in-register, then LDS-staged coalesced stores ----
    const int f = (MODE == 1) ? *flag : 0;
    if (MODE == 1) {
#pragma unroll
        for (int ni = 0; ni < 4; ++ni) {
            int col = bn + wn + ni * 16 + l15;
            float bv = f ? ((const float*)bias)[col] : (float)((const __bf16*)bias)[col];
#pragma unroll
            for (int mi = 0; mi < 4; ++mi)
#pragma unroll
                for (int rg = 0; rg < 4; ++rg) acc[mi][ni][rg] += bv;
        }
    }

    if (MODE == 0 || !f) {
        // bf16 output: 4 chunks of 32 rows; cs = [32][136] bf16 (8704 B)
        __bf16* cs = (__bf16*)smem;
#pragma unroll
        for (int c = 0; c < 4; ++c) {
            __syncthreads();
            if (wm == (c >> 1) * 64) {
                int mb = (c & 1) * 2;
#pragma unroll
                for (int mloc = 0; mloc < 2; ++mloc) {
                    int rowc = mloc * 16 + quad * 4;
#pragma unroll
                    for (int ni = 0; ni < 4; ++ni) {
                        int col = wn + ni * 16 + l15;
#pragma unroll
                        for (int rg = 0; rg < 4; ++rg)
                            cs[(rowc + rg) * 136 + col] = (__bf16)acc[mb + mloc][ni][rg];
                    }
                }
            }
            __syncthreads();
#pragma unroll
            for (int p = 0; p < 2; ++p) {
                int row  = p * 16 + (tid >> 4);
                int colc = tid & 15;
                bf16x8 v = *(const bf16x8*)&cs[row * 136 + colc * 8];
                *(bf16x8*)((__bf16*)Cout + (size_t)(bm + c * 32 + row) * ldc + bn + colc * 8) = v;
            }
        }
    } else {
        // fp32 output: 8 chunks of 16 rows; cs = [16][132] float (8448 B)
        float* cs = (float*)smem;
#pragma unroll
        for (int c = 0; c < 8; ++c) {
            __syncthreads();
            if (wm == (c >> 2) * 64) {
                int mi = c & 3;
                int rowc = quad * 4;
#pragma unroll
                for (int ni = 0; ni < 4; ++ni) {
                    int col = wn + ni * 16 + l15;
#pragma unroll
                    for (int rg = 0; rg < 4; ++rg)
                        cs[(rowc + rg) * 132 + col] = acc[mi][ni][rg];
                }
            }
            __syncthreads();
#pragma unroll
            for (int p = 0; p < 2; ++p) {
                int row  = p * 8 + (tid >> 5);
                int colc = tid & 31;
                float4 v = *(const float4*)&cs[row * 132 + colc * 4];
                *(float4*)((float*)Cout + (size_t)(bm + c * 16 + row) * ldc + bn + colc * 4) = v;
            }
        }
    }
}

// ---------------------------------------------------------------------------
// Flash attention, S^T formulation, async16 staging. Grid (B*H, N/128) --
// bh is blockIdx.x so id%8 = bh%8: all q-tiles of a head pin to one XCD.
// R13 structure + R15 WAR fence. R17: Ps pad 88 -> 68 (<=2-way conflicts,
// free) => LDS 50176 B => 3 blocks/CU (was 2) for +50% latency-hiding TLP;
// grid 1536 = exactly 2 dispatch rounds at 768 concurrent.
// LDS: K buf k @ k*8192; V buf k @ 16384 + k*8192; Ps @ 32768.
// ---------------------------------------------------------------------------
__global__ __launch_bounds__(256, 3)
void attn(const __bf16* qkv, const __bf16* __restrict__ vt,
          const int* __restrict__ perm, __bf16* O, int ldo) {
    __shared__ __align__(16) char smem[50176];
    __bf16* Qs = (__bf16*)smem;              // 128 x 64 (dies after qf loaded)
    __bf16* Ps = (__bf16*)(smem + 32768);    // 4 waves x [32 x 68]

    const int tid  = threadIdx.x;
    const int wid  = tid >> 6;
    const int lane = tid & 63;
    const int quad = lane >> 4;
    const int l15  = lane & 15;
    const int bh = blockIdx.x;
    const int q0 = blockIdx.y * 128;
    const int b = bh / 12, h = bh % 12;
    const size_t row_base = (size_t)b * 1024;
    const int qcol = h * 64;
    const int kcol = 768 + h * 64;
    const int srow8  = lane >> 3;
    const int sslot8 = lane & 7;
    __bf16* Pw = Ps + wid * (32 * 68);

    // ---- stage Q (perm-gathered rows) ----
#pragma unroll
    for (int is = 0; is < 4; ++is) {
        int r = is * 32 + wid * 8 + srow8;
        int gr = perm[q0 + r];
        int chunk = sslot8 ^ (r & 7);
        async16(qkv + (row_base + gr) * 2304 + qcol + chunk * 8,
                &Qs[(is * 32 + wid * 8) * 64]);
    }
    __syncthreads();

    bf16x8 qf[2][2];
#pragma unroll
    for (int mi = 0; mi < 2; ++mi) {
        int r = wid * 32 + mi * 16 + l15;
#pragma unroll
        for (int ks = 0; ks < 2; ++ks)
            qf[mi][ks] = *(const bf16x8*)&Qs[r * 64 + (((ks * 4 + quad) ^ (r & 7)) * 8)];
    }
    // my qf reads must complete before staging overwrites the Qs region
    asm volatile("s_waitcnt lgkmcnt(0)" ::: "memory");
    __builtin_amdgcn_sched_barrier(0);
    __builtin_amdgcn_s_barrier();

    // ---- loop-invariant LDS element offsets ----
    const int off0 = l15 * 64 + (((0 * 4 + quad) ^ (l15 & 7)) * 8); // ks/ks2 = 0
    const int off1 = l15 * 64 + (((1 * 4 + quad) ^ (l15 & 7)) * 8); // ks/ks2 = 1
    const int pwb  = l15 * 68 + quad * 4;   // + mi*1088 + ki*16 (immediates)
    const int pfb  = l15 * 68 + quad * 8;   // + mi*1088 + ks2*32 (immediates)

    // ---- held global staging pointers (incremented per stage) ----
    const int rK = wid * 8 + srow8;                 // +32 for second chunk
    const int ck = sslot8 ^ (rK & 7);               // (is*32)&7 == 0
    const __bf16* kg0 = qkv + (row_base + rK) * 2304 + kcol + ck * 8;
    const __bf16* kg1 = kg0 + (size_t)32 * 2304;
    const __bf16* vg0 = vt + ((size_t)bh * 64 + rK) * 1024 + ck * 8;
    const __bf16* vg1 = vg0 + (size_t)32 * 1024;

    f32x4 acco[2][4];
#pragma unroll
    for (int mi = 0; mi < 2; ++mi)
#pragma unroll
        for (int ni = 0; ni < 4; ++ni) acco[mi][ni] = (f32x4)0.0f;
    float lsum[2] = {0.0f, 0.0f};

    const float cfac = 0.125f * 1.44269504088896340736f;

    // stage into buf kb: K @ kb*8192, V @ 16384 + kb*8192
#define ASTAGE(KB, VB) do {                                             \
        async16(kg0, smem + (KB) + wid * 1024);                         \
        async16(kg1, smem + (KB) + 4096 + wid * 1024);                  \
        async16(vg0, smem + (VB) + wid * 1024);                         \
        async16(vg1, smem + (VB) + 4096 + wid * 1024);                  \
        kg0 += (size_t)64 * 2304; kg1 += (size_t)64 * 2304;             \
        vg0 += 64; vg1 += 64;                                           \
    } while (0)

    auto compute = [&](const __bf16* Kb, const __bf16* Vb) {
#pragma unroll
        for (int half = 0; half < 2; ++half) {
            // ---- QK^T for ki = half*2 .. half*2+1 ----
            f32x4 accs[2][2];
#pragma unroll
            for (int ki = 0; ki < 2; ++ki)
#pragma unroll
                for (int mi = 0; mi < 2; ++mi) accs[ki][mi] = (f32x4)0.0f;
#pragma unroll
            for (int ks = 0; ks < 2; ++ks) {
                const int off = ks ? off1 : off0;
                bf16x8 kf0 = *(const bf16x8*)&Kb[(half * 2 + 0) * 1024 + off];
                bf16x8 kf1 = *(const bf16x8*)&Kb[(half * 2 + 1) * 1024 + off];
                accs[0][0] = mfma16(kf0, qf[0][ks], accs[0][0]);
                accs[0][1] = mfma16(kf0, qf[1][ks], accs[0][1]);
                accs[1][0] = mfma16(kf1, qf[0][ks], accs[1][0]);
                accs[1][1] = mfma16(kf1, qf[1][ks], accs[1][1]);
            }

            // ---- softmax (static bias -8; cancels in normalization) ----
#pragma unroll
            for (int ki = 0; ki < 2; ++ki)
#pragma unroll
                for (int mi = 0; mi < 2; ++mi) {
                    bf16x4 pk;
                    float s0 = __builtin_amdgcn_exp2f(accs[ki][mi][0] * cfac - 8.0f);
                    float s1 = __builtin_amdgcn_exp2f(accs[ki][mi][1] * cfac - 8.0f);
                    float s2 = __builtin_amdgcn_exp2f(accs[ki][mi][2] * cfac - 8.0f);
                    float s3 = __builtin_amdgcn_exp2f(accs[ki][mi][3] * cfac - 8.0f);
                    pk[0] = (__bf16)s0; pk[1] = (__bf16)s1;
                    pk[2] = (__bf16)s2; pk[3] = (__bf16)s3;
                    lsum[mi] += (s0 + s1) + (s2 + s3);
                    *(bf16x4*)&Pw[pwb + mi * 1088 + (half * 2 + ki) * 16] = pk;
                }

            // ---- PV for ks2 = half (same-wave LDS RAW; lgkmcnt orders it) ----
            {
                bf16x8 pf0 = *(const bf16x8*)&Pw[pfb + 0 * 1088 + half * 32];
                bf16x8 pf1 = *(const bf16x8*)&Pw[pfb + 1 * 1088 + half * 32];
                const int offv = half ? off1 : off0;
#pragma unroll
                for (int ni = 0; ni < 4; ++ni) {
                    bf16x8 vf = *(const bf16x8*)&Vb[ni * 1024 + offv];
                    acco[0][ni] = mfma16(pf0, vf, acco[0][ni]);
                    acco[1][ni] = mfma16(pf1, vf, acco[1][ni]);
                }
            }
        }
    };

    // ---- prologue: stage kt=0 into buf0 ----
    ASTAGE(0, 16384);

    // ---- main loop: 16 kt, unrolled x2 for literal buffer offsets ----
#pragma unroll 1
    for (int kt2 = 0; kt2 < 8; ++kt2) {
        asm volatile("s_waitcnt vmcnt(0) lgkmcnt(0)" ::: "memory");
        __builtin_amdgcn_s_barrier();
        ASTAGE(8192, 16384 + 8192);
        compute((const __bf16*)smem, (const __bf16*)(smem + 16384));
        asm volatile("s_waitcnt vmcnt(0) lgkmcnt(0)" ::: "memory");
        __builtin_amdgcn_s_barrier();
        if (kt2 < 7) ASTAGE(0, 16384);
        compute((const __bf16*)(smem + 8192), (const __bf16*)(smem + 16384 + 8192));
    }
#undef ASTAGE

#pragma unroll
    for (int off = 16; off < 64; off <<= 1) {
        lsum[0] += __shfl_xor(lsum[0], off, 64);
        lsum[1] += __shfl_xor(lsum[1], off, 64);
    }

#pragma unroll
    for (int mi = 0; mi < 2; ++mi) {
#pragma unroll
        for (int rg = 0; rg < 4; ++rg) {
            float inv = 1.0f / __shfl(lsum[mi], quad * 4 + rg, 64);
            int orow = q0 + wid * 32 + mi * 16 + quad * 4 + rg;
#pragma unroll
            for (int ni = 0; ni < 4; ++ni) {
                int ocol = h * 64 + ni * 16 + l15;
                O[(row_base + orow) * (size_t)ldo + ocol] = (__bf16)(acco[mi][ni][rg] * inv);
            }
        }
    }
}

// ---------------------------------------------------------------------------
// Workspace layout (bytes), total ~130.5 MB (see round-3 comment).
// ---------------------------------------------------------------------------
extern "C" void kernel_launch(void* const* d_in, const int* in_sizes, int n_in,
                              void* d_out, int out_size, void* d_ws, size_t ws_size,
                              hipStream_t stream) {
    (void)in_sizes; (void)n_in; (void)out_size; (void)ws_size;
    const void* x_raw    = d_in[0];
    const void* Wqkv_raw = d_in[1];
    const void* Wout_raw = d_in[2];
    const void* bout_raw = d_in[3];
    const int*  perm     = (const int*)d_in[4];

    char* ws = (char*)d_ws;
    int*    flag = (int*)ws;
    __bf16* Xc   = (__bf16*)(ws + 256);
    __bf16* QKV  = (__bf16*)(ws + 25166080);
    __bf16* Vt   = (__bf16*)(ws + 100663552);
    __bf16* Wqt  = (__bf16*)(ws + 125829376);
    __bf16* Wot  = (__bf16*)(ws + 129368320);
    __bf16* Obuf = QKV + 1536; // O[n][768] in QKV's V columns, ld 2304

    prep<<<1600, 256, 0, stream>>>(x_raw, Xc, Wqkv_raw, Wqt, Wout_raw, Wot, flag);
    gemm_bt<0><<<dim3(128, 18), 256, 0, stream>>>(Xc, 768, Wqt, nullptr, QKV, 2304, 768, nullptr, Vt);
    attn<<<dim3(192, 8), 256, 0, stream>>>(QKV, Vt, perm, Obuf, 2304);
    gemm_bt<1><<<dim3(128, 6), 256, 0, stream>>>(Obuf, 2304, Wot, bout_raw, d_out, 768, 768, flag, nullptr);
}

// Round 12
// 197.979 us; speedup vs baseline: 1.0644x; 1.0644x over previous
//
#include <hip/hip_runtime.h>
#include <hip/hip_bf16.h>

// ---------------------------------------------------------------------------
// ShuffleRowAttention: B=16, N=1024, DIM=768, H=12, DH=64. fp32 in/out
// (runtime-detected). Round 18:
//  * R17 post-mortem: attn Ps-68/(256,3) change regressed 15-20 us (attn
//    98.6 us) and the predicted 3-blocks/CU never happened (Occupancy stayed
//    ~29% despite 147 KB <= 160 KB -- full LDS pool evidently not
//    concurrently allocatable). Reverted attn to the R15/R16 version
//    (Ps pad 88, launch_bounds(256,2), LDS 55296).
//  * Keepers, now combined for the first time: fused prep (R16), identity
//    M-fast GEMM tile mapping (R15/R17), triple-buffer counted-vmcnt GEMM
//    with lgkmcnt WAR fence (R15), Vt direct-write fused into gemm<0> (R13),
//    attn K/V double-buffer (R13).
// ---------------------------------------------------------------------------

typedef __bf16 bf16x8 __attribute__((ext_vector_type(8)));
typedef __bf16 bf16x4 __attribute__((ext_vector_type(4)));
typedef float  f32x4  __attribute__((ext_vector_type(4)));

__device__ __forceinline__ f32x4 mfma16(bf16x8 a, bf16x8 b, f32x4 c) {
    return __builtin_amdgcn_mfma_f32_16x16x32_bf16(a, b, c, 0, 0, 0);
}

// async 16B/lane global->LDS: lds base wave-uniform; lane i deposits at +16*i.
__device__ __forceinline__ void async16(const void* g, void* l) {
    __builtin_amdgcn_global_load_lds(
        (const __attribute__((address_space(1))) unsigned int*)g,
        (__attribute__((address_space(3))) unsigned int*)l,
        16, 0, 0);
}

// ---------------------------------------------------------------------------
// Fused prep: dtype-detect (per block, from its own source) + X fp32->bf16
// convert + Wqkv/Wout transpose. Blocks [0,1024): convert X; [1024,1456):
// transpose Wqkv (768x2304); [1456,1600): transpose Wout (768x768).
// Detector: fp32 data viewed as uint16 halves -> ~25% of low halves have
// exponent-field >= 0xC0 (mantissa bits ~uniform); true bf16 N(0,sigma)
// never does. Scale-invariant -> valid per-source. Block 0 publishes flag.
// ---------------------------------------------------------------------------
__global__ __launch_bounds__(256)
void prep(const void* __restrict__ x, __bf16* __restrict__ Xc,
          const void* __restrict__ Wqkv, __bf16* __restrict__ Wqt,
          const void* __restrict__ Wout, __bf16* __restrict__ Wot,
          int* __restrict__ flag) {
    __shared__ __bf16 tile[64][65];
    __shared__ int cnt;
    const int bid = blockIdx.x;
    const int tid = threadIdx.x;

    const unsigned short* raw =
        (bid < 1024) ? (const unsigned short*)x
                     : (bid < 1456) ? (const unsigned short*)Wqkv
                                    : (const unsigned short*)Wout;
    if (tid == 0) cnt = 0;
    __syncthreads();
    int local = 0;
    for (int i = tid; i < 2048; i += 256) {
        unsigned e = (raw[i] >> 7) & 0xFFu;
        if (e >= 0xC0u) local++;
    }
    atomicAdd(&cnt, local);
    __syncthreads();
    const int f = (cnt > 16) ? 1 : 0;
    if (bid == 0 && tid == 0) *flag = f;

    if (bid < 1024) {
        // ---- convert X: grid-stride over 16384*768/4 float4-groups ----
        const int n4 = 16384 * 768 / 4;
        int i = bid * 256 + tid;
        const int stride = 1024 * 256;
        if (f) {
            const float4* s = (const float4*)x;
            for (; i < n4; i += stride) {
                float4 v = s[i];
                bf16x4 o;
                o[0] = (__bf16)v.x; o[1] = (__bf16)v.y;
                o[2] = (__bf16)v.z; o[3] = (__bf16)v.w;
                *(bf16x4*)&Xc[(size_t)i * 4] = o;
            }
        } else {
            const ushort4* s = (const ushort4*)x;
            for (; i < n4; i += stride) *(ushort4*)&Xc[(size_t)i * 4] = s[i];
        }
    } else {
        // ---- transpose W (64x64 tile via LDS) ----
        const void* in;
        __bf16* out;
        int R, C, c0, r0;
        if (bid < 1456) {
            int t = bid - 1024;           // 36 x 12 tiles
            in = Wqkv; out = Wqt; R = 768; C = 2304;
            c0 = (t % 36) * 64; r0 = (t / 36) * 64;
        } else {
            int t = bid - 1456;           // 12 x 12 tiles
            in = Wout; out = Wot; R = 768; C = 768;
            c0 = (t % 12) * 64; r0 = (t / 12) * 64;
        }
        const int tx = tid & 63, ty = tid >> 6;
#pragma unroll
        for (int k = 0; k < 16; ++k) {
            int r = ty + 4 * k;
            size_t idx = (size_t)(r0 + r) * C + c0 + tx;
            tile[r][tx] = f ? (__bf16)((const float*)in)[idx] : ((const __bf16*)in)[idx];
        }
        __syncthreads();
#pragma unroll
        for (int k = 0; k < 16; ++k) {
            int cc = ty + 4 * k;
            out[(size_t)(c0 + cc) * R + r0 + tx] = tile[tx][cc];
        }
    }
}

// ---------------------------------------------------------------------------
// GEMM: C[M x N] = A[M x K] * Bt[N x K]^T (+ bias); bf16 in, fp32 acc.
// 128x128 tile, BK=32, 4 waves, 16x16x32 MFMA. R15 structure:
//  - LDS TRIPLE buffer: buf b at smem + b*16384 { A[128x32] @ +0, B @ +8192 }.
//    16B-chunk slot s of row r holds global chunk s^((r>>1)&3) (XOR swizzle,
//    conflict-free ds_read_b128; staged via pre-swizzled global col).
//  - Tile kt: { s_waitcnt vmcnt(4) lgkmcnt(0); s_barrier; stage(kt+2) ->
//    buf (kt+2)%3; 8x ds_read_b128 + 16 MFMA on buf kt%3 }.
//  - Identity tile mapping, M-fast dispatch (R16 swap hurt: FETCH 2x).
//  - nkt = K/32 must be 24 (K=768): 7 literal groups of 3 + 3-tile tail.
// MODE 0: C bf16, no bias; V-range blocks (bn>=1536) write transposed to vt
//         instead of Cout (QKV V cols are dead -- O overwrites them).
// MODE 1: C/bias dtype per flag.
// ---------------------------------------------------------------------------
#define GMFMA16()                                                       \
    acc[0][0] = mfma16(af0, bf0, acc[0][0]);                            \
    acc[0][1] = mfma16(af0, bf1, acc[0][1]);                            \
    acc[0][2] = mfma16(af0, bf2, acc[0][2]);                            \
    acc[0][3] = mfma16(af0, bf3, acc[0][3]);                            \
    acc[1][0] = mfma16(af1, bf0, acc[1][0]);                            \
    acc[1][1] = mfma16(af1, bf1, acc[1][1]);                            \
    acc[1][2] = mfma16(af1, bf2, acc[1][2]);                            \
    acc[1][3] = mfma16(af1, bf3, acc[1][3]);                            \
    acc[2][0] = mfma16(af2, bf0, acc[2][0]);                            \
    acc[2][1] = mfma16(af2, bf1, acc[2][1]);                            \
    acc[2][2] = mfma16(af2, bf2, acc[2][2]);                            \
    acc[2][3] = mfma16(af2, bf3, acc[2][3]);                            \
    acc[3][0] = mfma16(af3, bf0, acc[3][0]);                            \
    acc[3][1] = mfma16(af3, bf1, acc[3][1]);                            \
    acc[3][2] = mfma16(af3, bf2, acc[3][2]);                            \
    acc[3][3] = mfma16(af3, bf3, acc[3][3])

// Tile step. RD/ST: literal byte offsets of read/stage buffers.
// VMK: 4 -> vmcnt(4), 0 -> vmcnt(0). Wait at TOP pins prior ds_reads
// complete (lgkmcnt) AND tile kt's staging landed (vmcnt), then barrier,
// then stage, then compute.
#define GTILE(RD, ST, DO_STAGE, VMK) do {                               \
    if ((VMK) == 4)                                                     \
        asm volatile("s_waitcnt vmcnt(4) lgkmcnt(0)" ::: "memory");     \
    else                                                                \
        asm volatile("s_waitcnt vmcnt(0) lgkmcnt(0)" ::: "memory");     \
    __builtin_amdgcn_s_barrier();                                       \
    if (DO_STAGE) {                                                     \
        async16(gA0, smem + (ST) + stA0);                               \
        async16(gA1, smem + (ST) + stA1);                               \
        async16(gB0, smem + (ST) + 8192 + stA0);                        \
        async16(gB1, smem + (ST) + 8192 + stA1);                        \
        gA0 += 32; gA1 += 32; gB0 += 32; gB1 += 32;                     \
    }                                                                   \
    bf16x8 af0 = *(const bf16x8*)(smem + (RD) + aoff0);                 \
    bf16x8 af1 = *(const bf16x8*)(smem + (RD) + aoff1);                 \
    bf16x8 af2 = *(const bf16x8*)(smem + (RD) + aoff2);                 \
    bf16x8 af3 = *(const bf16x8*)(smem + (RD) + aoff3);                 \
    bf16x8 bf0 = *(const bf16x8*)(smem + (RD) + boff0);                 \
    bf16x8 bf1 = *(const bf16x8*)(smem + (RD) + boff1);                 \
    bf16x8 bf2 = *(const bf16x8*)(smem + (RD) + boff2);                 \
    bf16x8 bf3 = *(const bf16x8*)(smem + (RD) + boff3);                 \
    GMFMA16();                                                          \
} while (0)

template <int MODE>
__global__ __launch_bounds__(256, 3)
void gemm_bt(const __bf16* __restrict__ A, int lda,
             const __bf16* __restrict__ Bt,
             const void* __restrict__ bias,
             void* __restrict__ Cout, int ldc,
             int K, const int* __restrict__ flag,
             __bf16* __restrict__ vt) {
    __shared__ __align__(16) char smem[49152];
    const int tid  = threadIdx.x;
    const int wid  = tid >> 6;
    const int lane = tid & 63;
    const int quad = lane >> 4;
    const int l15  = lane & 15;

    // identity tile mapping, M-fast (R16 swap reverted)
    const int bm = blockIdx.x * 128;
    const int bn = blockIdx.y * 128;

    const int wm = (wid & 1) * 64;
    const int wn = (wid >> 1) * 64;
    const int srow  = lane >> 2;
    const int sslot = lane & 3;

    // held staging pointers (global chunk pre-swizzled: slot s <- chunk
    // s^((r>>1)&3), deposited linearly at LDS slot sslot)
    const int rA0 = wid * 16 + srow;
    const int rA1 = 64 + wid * 16 + srow;
    const __bf16* gA0 = A  + (size_t)(bm + rA0) * lda + ((sslot ^ ((rA0 >> 1) & 3)) << 3);
    const __bf16* gA1 = A  + (size_t)(bm + rA1) * lda + ((sslot ^ ((rA1 >> 1) & 3)) << 3);
    const __bf16* gB0 = Bt + (size_t)(bn + rA0) * K   + ((sslot ^ ((rA0 >> 1) & 3)) << 3);
    const __bf16* gB1 = Bt + (size_t)(bn + rA1) * K   + ((sslot ^ ((rA1 >> 1) & 3)) << 3);
    const int stA0 = (wid * 16) * 64;        // + lane*16 implicit (bytes)
    const int stA1 = (64 + wid * 16) * 64;

    // frag read byte offsets (loop-invariant; buffer base is a literal)
    const int rf0 = wm + 0 * 16 + l15, rf1 = wm + 1 * 16 + l15;
    const int rf2 = wm + 2 * 16 + l15, rf3 = wm + 3 * 16 + l15;
    const int aoff0 = rf0 * 64 + ((quad ^ ((rf0 >> 1) & 3)) * 16);
    const int aoff1 = rf1 * 64 + ((quad ^ ((rf1 >> 1) & 3)) * 16);
    const int aoff2 = rf2 * 64 + ((quad ^ ((rf2 >> 1) & 3)) * 16);
    const int aoff3 = rf3 * 64 + ((quad ^ ((rf3 >> 1) & 3)) * 16);
    const int rg0 = wn + 0 * 16 + l15, rg1 = wn + 1 * 16 + l15;
    const int rg2 = wn + 2 * 16 + l15, rg3 = wn + 3 * 16 + l15;
    const int boff0 = 8192 + rg0 * 64 + ((quad ^ ((rg0 >> 1) & 3)) * 16);
    const int boff1 = 8192 + rg1 * 64 + ((quad ^ ((rg1 >> 1) & 3)) * 16);
    const int boff2 = 8192 + rg2 * 64 + ((quad ^ ((rg2 >> 1) & 3)) * 16);
    const int boff3 = 8192 + rg3 * 64 + ((quad ^ ((rg3 >> 1) & 3)) * 16);

    f32x4 acc[4][4];
#pragma unroll
    for (int i = 0; i < 4; ++i)
#pragma unroll
        for (int j = 0; j < 4; ++j) acc[i][j] = (f32x4)0.0f;

    // ---- prologue: stage tile 0 -> buf0, tile 1 -> buf1 (8 loads in flight).
    async16(gA0, smem + stA0);
    async16(gA1, smem + stA1);
    async16(gB0, smem + 8192 + stA0);
    async16(gB1, smem + 8192 + stA1);
    gA0 += 32; gA1 += 32; gB0 += 32; gB1 += 32;
    async16(gA0, smem + 16384 + stA0);
    async16(gA1, smem + 16384 + stA1);
    async16(gB0, smem + 16384 + 8192 + stA0);
    async16(gB1, smem + 16384 + 8192 + stA1);
    gA0 += 32; gA1 += 32; gB0 += 32; gB1 += 32;

    // ---- main loop: nkt = 24 tiles = 7 literal groups of 3 + 3-tile tail ----
#pragma unroll 1
    for (int g = 0; g < 7; ++g) {
        GTILE(0,     32768, true, 4);   // tile 3g+0: read buf0, stage -> buf2
        GTILE(16384, 0,     true, 4);   // tile 3g+1: read buf1, stage -> buf0
        GTILE(32768, 16384, true, 4);   // tile 3g+2: read buf2, stage -> buf1
    }
    GTILE(0,     32768, true,  4);      // tile 21: stages tile 23 -> buf2
    GTILE(16384, 0,     false, 4);      // tile 22
    GTILE(32768, 0,     false, 0);      // tile 23: final drain

    // ---- MODE 0 V-range blocks: write acc transposed to Vt, skip Cout ----
    if (MODE == 0 && bn >= 1536) {
        const int bq = bm >> 10;                         // batch index
        const int n0 = (bm & 1023) + wm + quad * 4;      // n base for this lane
        const int colb = bn - 1536 + wn;                 // V feature base
        // vt row = (b*12 + col/64)*64 + col%64 = b*768 + col
#pragma unroll
        for (int mi = 0; mi < 4; ++mi)
#pragma unroll
            for (int ni = 0; ni < 4; ++ni) {
                int col = colb + ni * 16 + l15;
                bf16x4 v;
                v[0] = (__bf16)acc[mi][ni][0];
                v[1] = (__bf16)acc[mi][ni][1];
                v[2] = (__bf16)acc[mi][ni][2];
                v[3] = (__bf16)acc[mi][ni][3];
                *(bf16x4*)&vt[((size_t)bq * 768 + col) * 1024 + n0 + mi * 16] = v;
            }
        return;   // block-uniform branch; no barriers skipped asymmetrically
    }

    // ---- epilogue: bias add in-register, then LDS-staged coalesced stores ----
    const int f = (MODE == 1) ? *flag : 0;
    if (MODE == 1) {
#pragma unroll
        for (int ni = 0; ni < 4; ++ni) {
            int col = bn + wn + ni * 16 + l15;
            float bv = f ? ((const float*)bias)[col] : (float)((const __bf16*)bias)[col];
#pragma unroll
            for (int mi = 0; mi < 4; ++mi)
#pragma unroll
                for (int rg = 0; rg < 4; ++rg) acc[mi][ni][rg] += bv;
        }
    }

    if (MODE == 0 || !f) {
        // bf16 output: 4 chunks of 32 rows; cs = [32][136] bf16 (8704 B)
        __bf16* cs = (__bf16*)smem;
#pragma unroll
        for (int c = 0; c < 4; ++c) {
            __syncthreads();
            if (wm == (c >> 1) * 64) {
                int mb = (c & 1) * 2;
#pragma unroll
                for (int mloc = 0; mloc < 2; ++mloc) {
                    int rowc = mloc * 16 + quad * 4;
#pragma unroll
                    for (int ni = 0; ni < 4; ++ni) {
                        int col = wn + ni * 16 + l15;
#pragma unroll
                        for (int rg = 0; rg < 4; ++rg)
                            cs[(rowc + rg) * 136 + col] = (__bf16)acc[mb + mloc][ni][rg];
                    }
                }
            }
            __syncthreads();
#pragma unroll
            for (int p = 0; p < 2; ++p) {
                int row  = p * 16 + (tid >> 4);
                int colc = tid & 15;
                bf16x8 v = *(const bf16x8*)&cs[row * 136 + colc * 8];
                *(bf16x8*)((__bf16*)Cout + (size_t)(bm + c * 32 + row) * ldc + bn + colc * 8) = v;
            }
        }
    } else {
        // fp32 output: 8 chunks of 16 rows; cs = [16][132] float (8448 B)
        float* cs = (float*)smem;
#pragma unroll
        for (int c = 0; c < 8; ++c) {
            __syncthreads();
            if (wm == (c >> 2) * 64) {
                int mi = c & 3;
                int rowc = quad * 4;
#pragma unroll
                for (int ni = 0; ni < 4; ++ni) {
                    int col = wn + ni * 16 + l15;
#pragma unroll
                    for (int rg = 0; rg < 4; ++rg)
                        cs[(rowc + rg) * 132 + col] = acc[mi][ni][rg];
                }
            }
            __syncthreads();
#pragma unroll
            for (int p = 0; p < 2; ++p) {
                int row  = p * 8 + (tid >> 5);
                int colc = tid & 31;
                float4 v = *(const float4*)&cs[row * 132 + colc * 4];
                *(float4*)((float*)Cout + (size_t)(bm + c * 16 + row) * ldc + bn + colc * 4) = v;
            }
        }
    }
}

// ---------------------------------------------------------------------------
// Flash attention, S^T formulation, async16 staging. Grid (B*H, N/128) --
// bh is blockIdx.x so id%8 = bh%8: all q-tiles of a head pin to one XCD.
// R15/R16 configuration (R17's Ps-68/(256,3) regressed; reverted):
// K/V double-buffered; per-kt wait vmcnt(0)+lgkmcnt(0) (WAR fence) +
// s_barrier; stage(kt+1) issued right after the barrier.
// LDS: K buf k @ k*8192; V buf k @ 16384 + k*8192; Ps @ 32768 (55296 total).
// ---------------------------------------------------------------------------
__global__ __launch_bounds__(256, 2)
void attn(const __bf16* qkv, const __bf16* __restrict__ vt,
          const int* __restrict__ perm, __bf16* O, int ldo) {
    __shared__ __align__(16) char smem[55296];
    __bf16* Qs = (__bf16*)smem;              // 128 x 64 (dies after qf loaded)
    __bf16* Ps = (__bf16*)(smem + 32768);    // 4 waves x [32 x 88]

    const int tid  = threadIdx.x;
    const int wid  = tid >> 6;
    const int lane = tid & 63;
    const int quad = lane >> 4;
    const int l15  = lane & 15;
    const int bh = blockIdx.x;
    const int q0 = blockIdx.y * 128;
    const int b = bh / 12, h = bh % 12;
    const size_t row_base = (size_t)b * 1024;
    const int qcol = h * 64;
    const int kcol = 768 + h * 64;
    const int srow8  = lane >> 3;
    const int sslot8 = lane & 7;
    __bf16* Pw = Ps + wid * (32 * 88);

    // ---- stage Q (perm-gathered rows) ----
#pragma unroll
    for (int is = 0; is < 4; ++is) {
        int r = is * 32 + wid * 8 + srow8;
        int gr = perm[q0 + r];
        int chunk = sslot8 ^ (r & 7);
        async16(qkv + (row_base + gr) * 2304 + qcol + chunk * 8,
                &Qs[(is * 32 + wid * 8) * 64]);
    }
    __syncthreads();

    bf16x8 qf[2][2];
#pragma unroll
    for (int mi = 0; mi < 2; ++mi) {
        int r = wid * 32 + mi * 16 + l15;
#pragma unroll
        for (int ks = 0; ks < 2; ++ks)
            qf[mi][ks] = *(const bf16x8*)&Qs[r * 64 + (((ks * 4 + quad) ^ (r & 7)) * 8)];
    }
    // my qf reads must complete before staging overwrites the Qs region
    asm volatile("s_waitcnt lgkmcnt(0)" ::: "memory");
    __builtin_amdgcn_sched_barrier(0);
    __builtin_amdgcn_s_barrier();

    // ---- loop-invariant LDS element offsets ----
    const int off0 = l15 * 64 + (((0 * 4 + quad) ^ (l15 & 7)) * 8); // ks/ks2 = 0
    const int off1 = l15 * 64 + (((1 * 4 + quad) ^ (l15 & 7)) * 8); // ks/ks2 = 1
    const int pwb  = l15 * 88 + quad * 4;   // + mi*1408 + ki*16 (immediates)
    const int pfb  = l15 * 88 + quad * 8;   // + mi*1408 + ks2*32 (immediates)

    // ---- held global staging pointers (incremented per stage) ----
    const int rK = wid * 8 + srow8;                 // +32 for second chunk
    const int ck = sslot8 ^ (rK & 7);               // (is*32)&7 == 0
    const __bf16* kg0 = qkv + (row_base + rK) * 2304 + kcol + ck * 8;
    const __bf16* kg1 = kg0 + (size_t)32 * 2304;
    const __bf16* vg0 = vt + ((size_t)bh * 64 + rK) * 1024 + ck * 8;
    const __bf16* vg1 = vg0 + (size_t)32 * 1024;

    f32x4 acco[2][4];
#pragma unroll
    for (int mi = 0; mi < 2; ++mi)
#pragma unroll
        for (int ni = 0; ni < 4; ++ni) acco[mi][ni] = (f32x4)0.0f;
    float lsum[2] = {0.0f, 0.0f};

    const float cfac = 0.125f * 1.44269504088896340736f;

    // stage into buf kb: K @ kb*8192, V @ 16384 + kb*8192
#define ASTAGE(KB, VB) do {                                             \
        async16(kg0, smem + (KB) + wid * 1024);                         \
        async16(kg1, smem + (KB) + 4096 + wid * 1024);                  \
        async16(vg0, smem + (VB) + wid * 1024);                         \
        async16(vg1, smem + (VB) + 4096 + wid * 1024);                  \
        kg0 += (size_t)64 * 2304; kg1 += (size_t)64 * 2304;             \
        vg0 += 64; vg1 += 64;                                           \
    } while (0)

    auto compute = [&](const __bf16* Kb, const __bf16* Vb) {
#pragma unroll
        for (int half = 0; half < 2; ++half) {
            // ---- QK^T for ki = half*2 .. half*2+1 ----
            f32x4 accs[2][2];
#pragma unroll
            for (int ki = 0; ki < 2; ++ki)
#pragma unroll
                for (int mi = 0; mi < 2; ++mi) accs[ki][mi] = (f32x4)0.0f;
#pragma unroll
            for (int ks = 0; ks < 2; ++ks) {
                const int off = ks ? off1 : off0;
                bf16x8 kf0 = *(const bf16x8*)&Kb[(half * 2 + 0) * 1024 + off];
                bf16x8 kf1 = *(const bf16x8*)&Kb[(half * 2 + 1) * 1024 + off];
                accs[0][0] = mfma16(kf0, qf[0][ks], accs[0][0]);
                accs[0][1] = mfma16(kf0, qf[1][ks], accs[0][1]);
                accs[1][0] = mfma16(kf1, qf[0][ks], accs[1][0]);
                accs[1][1] = mfma16(kf1, qf[1][ks], accs[1][1]);
            }

            // ---- softmax (static bias -8; cancels in normalization) ----
#pragma unroll
            for (int ki = 0; ki < 2; ++ki)
#pragma unroll
                for (int mi = 0; mi < 2; ++mi) {
                    bf16x4 pk;
                    float s0 = __builtin_amdgcn_exp2f(accs[ki][mi][0] * cfac - 8.0f);
                    float s1 = __builtin_amdgcn_exp2f(accs[ki][mi][1] * cfac - 8.0f);
                    float s2 = __builtin_amdgcn_exp2f(accs[ki][mi][2] * cfac - 8.0f);
                    float s3 = __builtin_amdgcn_exp2f(accs[ki][mi][3] * cfac - 8.0f);
                    pk[0] = (__bf16)s0; pk[1] = (__bf16)s1;
                    pk[2] = (__bf16)s2; pk[3] = (__bf16)s3;
                    lsum[mi] += (s0 + s1) + (s2 + s3);
                    *(bf16x4*)&Pw[pwb + mi * 1408 + (half * 2 + ki) * 16] = pk;
                }

            // ---- PV for ks2 = half (same-wave LDS RAW; lgkmcnt orders it) ----
            {
                bf16x8 pf0 = *(const bf16x8*)&Pw[pfb + 0 * 1408 + half * 32];
                bf16x8 pf1 = *(const bf16x8*)&Pw[pfb + 1 * 1408 + half * 32];
                const int offv = half ? off1 : off0;
#pragma unroll
                for (int ni = 0; ni < 4; ++ni) {
                    bf16x8 vf = *(const bf16x8*)&Vb[ni * 1024 + offv];
                    acco[0][ni] = mfma16(pf0, vf, acco[0][ni]);
                    acco[1][ni] = mfma16(pf1, vf, acco[1][ni]);
                }
            }
        }
    };

    // ---- prologue: stage kt=0 into buf0 ----
    ASTAGE(0, 16384);

    // ---- main loop: 16 kt, unrolled x2 for literal buffer offsets ----
#pragma unroll 1
    for (int kt2 = 0; kt2 < 8; ++kt2) {
        asm volatile("s_waitcnt vmcnt(0) lgkmcnt(0)" ::: "memory");
        __builtin_amdgcn_s_barrier();
        ASTAGE(8192, 16384 + 8192);
        compute((const __bf16*)smem, (const __bf16*)(smem + 16384));
        asm volatile("s_waitcnt vmcnt(0) lgkmcnt(0)" ::: "memory");
        __builtin_amdgcn_s_barrier();
        if (kt2 < 7) ASTAGE(0, 16384);
        compute((const __bf16*)(smem + 8192), (const __bf16*)(smem + 16384 + 8192));
    }
#undef ASTAGE

#pragma unroll
    for (int off = 16; off < 64; off <<= 1) {
        lsum[0] += __shfl_xor(lsum[0], off, 64);
        lsum[1] += __shfl_xor(lsum[1], off, 64);
    }

#pragma unroll
    for (int mi = 0; mi < 2; ++mi) {
#pragma unroll
        for (int rg = 0; rg < 4; ++rg) {
            float inv = 1.0f / __shfl(lsum[mi], quad * 4 + rg, 64);
            int orow = q0 + wid * 32 + mi * 16 + quad * 4 + rg;
#pragma unroll
            for (int ni = 0; ni < 4; ++ni) {
                int ocol = h * 64 + ni * 16 + l15;
                O[(row_base + orow) * (size_t)ldo + ocol] = (__bf16)(acco[mi][ni][rg] * inv);
            }
        }
    }
}

// ---------------------------------------------------------------------------
// Workspace layout (bytes), total ~130.5 MB (see round-3 comment).
// ---------------------------------------------------------------------------
extern "C" void kernel_launch(void* const* d_in, const int* in_sizes, int n_in,
                              void* d_out, int out_size, void* d_ws, size_t ws_size,
                              hipStream_t stream) {
    (void)in_sizes; (void)n_in; (void)out_size; (void)ws_size;
    const void* x_raw    = d_in[0];
    const void* Wqkv_raw = d_in[1];
    const void* Wout_raw = d_in[2];
    const void* bout_raw = d_in[3];
    const int*  perm     = (const int*)d_in[4];

    char* ws = (char*)d_ws;
    int*    flag = (int*)ws;
    __bf16* Xc   = (__bf16*)(ws + 256);
    __bf16* QKV  = (__bf16*)(ws + 25166080);
    __bf16* Vt   = (__bf16*)(ws + 100663552);
    __bf16* Wqt  = (__bf16*)(ws + 125829376);
    __bf16* Wot  = (__bf16*)(ws + 129368320);
    __bf16* Obuf = QKV + 1536; // O[n][768] in QKV's V columns, ld 2304

    prep<<<1600, 256, 0, stream>>>(x_raw, Xc, Wqkv_raw, Wqt, Wout_raw, Wot, flag);
    gemm_bt<0><<<dim3(128, 18), 256, 0, stream>>>(Xc, 768, Wqt, nullptr, QKV, 2304, 768, nullptr, Vt);
    attn<<<dim3(192, 8), 256, 0, stream>>>(QKV, Vt, perm, Obuf, 2304);
    gemm_bt<1><<<dim3(128, 6), 256, 0, stream>>>(Obuf, 2304, Wot, bout_raw, d_out, 768, 768, flag, nullptr);
}

// Round 13
// 193.338 us; speedup vs baseline: 1.0899x; 1.0240x over previous
//
#include <hip/hip_runtime.h>
#include <hip/hip_bf16.h>

// ---------------------------------------------------------------------------
// ShuffleRowAttention: B=16, N=1024, DIM=768, H=12, DH=64. fp32 in/out
// (runtime-detected). Round 19:
//  * R18 = 198 us (best). gemm still 29% MfmaUtil, nothing saturated.
//  * Audit of "shape ceiling": every big-tile attempt had a confounder
//    (R9: 1 blk/CU + drain; R10: broken swizzle 5.3M conflicts + 1 blk/CU).
//    m233 says the 2-phase gap is PER-BARRIER overhead -> the untested clean
//    config is "2x MFMA per barrier + correct swizzle + counted vmcnt +
//    2 blk/CU".
//  * GEMM template -> 256x128 tile, BK=32, 4 waves (wave tile 128x64:
//    acc[8][4], 32 MFMA + 12 ds_read per tile per wave), TRIPLE buffer
//    (3 x 24576 B = 72 KB -> 2 blk/CU), counted vmcnt(6)+lgkmcnt(0).
//    Epilogues re-derived for 256 rows (8x32-row bf16 chunks / 16x16-row
//    fp32 chunks / V-range mi 0..7). Grids (64,18) and (64,6).
//  * attn / prep unchanged from R18.
// ---------------------------------------------------------------------------

typedef __bf16 bf16x8 __attribute__((ext_vector_type(8)));
typedef __bf16 bf16x4 __attribute__((ext_vector_type(4)));
typedef float  f32x4  __attribute__((ext_vector_type(4)));

__device__ __forceinline__ f32x4 mfma16(bf16x8 a, bf16x8 b, f32x4 c) {
    return __builtin_amdgcn_mfma_f32_16x16x32_bf16(a, b, c, 0, 0, 0);
}

// async 16B/lane global->LDS: lds base wave-uniform; lane i deposits at +16*i.
__device__ __forceinline__ void async16(const void* g, void* l) {
    __builtin_amdgcn_global_load_lds(
        (const __attribute__((address_space(1))) unsigned int*)g,
        (__attribute__((address_space(3))) unsigned int*)l,
        16, 0, 0);
}

// ---------------------------------------------------------------------------
// Fused prep: dtype-detect (per block, from its own source) + X fp32->bf16
// convert + Wqkv/Wout transpose. Blocks [0,1024): convert X; [1024,1456):
// transpose Wqkv (768x2304); [1456,1600): transpose Wout (768x768).
// ---------------------------------------------------------------------------
__global__ __launch_bounds__(256)
void prep(const void* __restrict__ x, __bf16* __restrict__ Xc,
          const void* __restrict__ Wqkv, __bf16* __restrict__ Wqt,
          const void* __restrict__ Wout, __bf16* __restrict__ Wot,
          int* __restrict__ flag) {
    __shared__ __bf16 tile[64][65];
    __shared__ int cnt;
    const int bid = blockIdx.x;
    const int tid = threadIdx.x;

    const unsigned short* raw =
        (bid < 1024) ? (const unsigned short*)x
                     : (bid < 1456) ? (const unsigned short*)Wqkv
                                    : (const unsigned short*)Wout;
    if (tid == 0) cnt = 0;
    __syncthreads();
    int local = 0;
    for (int i = tid; i < 2048; i += 256) {
        unsigned e = (raw[i] >> 7) & 0xFFu;
        if (e >= 0xC0u) local++;
    }
    atomicAdd(&cnt, local);
    __syncthreads();
    const int f = (cnt > 16) ? 1 : 0;
    if (bid == 0 && tid == 0) *flag = f;

    if (bid < 1024) {
        const int n4 = 16384 * 768 / 4;
        int i = bid * 256 + tid;
        const int stride = 1024 * 256;
        if (f) {
            const float4* s = (const float4*)x;
            for (; i < n4; i += stride) {
                float4 v = s[i];
                bf16x4 o;
                o[0] = (__bf16)v.x; o[1] = (__bf16)v.y;
                o[2] = (__bf16)v.z; o[3] = (__bf16)v.w;
                *(bf16x4*)&Xc[(size_t)i * 4] = o;
            }
        } else {
            const ushort4* s = (const ushort4*)x;
            for (; i < n4; i += stride) *(ushort4*)&Xc[(size_t)i * 4] = s[i];
        }
    } else {
        const void* in;
        __bf16* out;
        int R, C, c0, r0;
        if (bid < 1456) {
            int t = bid - 1024;           // 36 x 12 tiles
            in = Wqkv; out = Wqt; R = 768; C = 2304;
            c0 = (t % 36) * 64; r0 = (t / 36) * 64;
        } else {
            int t = bid - 1456;           // 12 x 12 tiles
            in = Wout; out = Wot; R = 768; C = 768;
            c0 = (t % 12) * 64; r0 = (t / 12) * 64;
        }
        const int tx = tid & 63, ty = tid >> 6;
#pragma unroll
        for (int k = 0; k < 16; ++k) {
            int r = ty + 4 * k;
            size_t idx = (size_t)(r0 + r) * C + c0 + tx;
            tile[r][tx] = f ? (__bf16)((const float*)in)[idx] : ((const __bf16*)in)[idx];
        }
        __syncthreads();
#pragma unroll
        for (int k = 0; k < 16; ++k) {
            int cc = ty + 4 * k;
            out[(size_t)(c0 + cc) * R + r0 + tx] = tile[tx][cc];
        }
    }
}

// ---------------------------------------------------------------------------
// GEMM: C[M x N] = A[M x K] * Bt[N x K]^T (+ bias); bf16 in, fp32 acc.
// Round 19: 256x128 tile, BK=32, 4 waves (wave tile 128x64), 16x16x32 MFMA.
//  - LDS TRIPLE buffer: buf b at smem + b*24576 { A[256x32] @ +0 (16 KB),
//    B[128x32] @ +16384 (8 KB) }. 16B-chunk slot s of row r holds global
//    chunk s^((r>>1)&3) (XOR swizzle; conflict-free ds_read_b128; staged via
//    pre-swizzled global col). 72 KB total -> 2 blocks/CU.
//  - Tile kt: { s_waitcnt vmcnt(6) lgkmcnt(0); s_barrier; stage(kt+2) ->
//    buf (kt+2)%3 (6 async16/wave); 12x ds_read_b128 + 32 MFMA on buf kt%3 }.
//    2x MFMA per barrier vs the 128^2 template (m233: per-barrier overhead
//    is the binder); 6 youngest loads stay in flight across every barrier.
//  - Identity tile mapping, M-fast dispatch.
//  - nkt = K/32 must be 24 (K=768): 7 literal groups of 3 + 3-tile tail.
// MODE 0: C bf16, no bias; V-range blocks (bn>=1536) write transposed to vt.
// MODE 1: C/bias dtype per flag.
// ---------------------------------------------------------------------------
#define GM4(MI, AF)                                                     \
    acc[MI][0] = mfma16(AF, bq0, acc[MI][0]);                           \
    acc[MI][1] = mfma16(AF, bq1, acc[MI][1]);                           \
    acc[MI][2] = mfma16(AF, bq2, acc[MI][2]);                           \
    acc[MI][3] = mfma16(AF, bq3, acc[MI][3])

#define GSTAGE(ST) do {                                                 \
    async16(gA0, smem + (ST) + stA);                                    \
    async16(gA1, smem + (ST) + stA + 1024);                             \
    async16(gA2, smem + (ST) + stA + 2048);                             \
    async16(gA3, smem + (ST) + stA + 3072);                             \
    async16(gB0, smem + (ST) + 16384 + stB);                            \
    async16(gB1, smem + (ST) + 16384 + stB + 1024);                     \
    gA0 += 32; gA1 += 32; gA2 += 32; gA3 += 32;                         \
    gB0 += 32; gB1 += 32;                                               \
} while (0)

// VMK: 6 -> vmcnt(6), 0 -> vmcnt(0). Wait at TOP (prior ds_reads complete +
// this tile's staging landed), barrier, stage, read frags, 32 MFMA.
#define GTILE(RD, ST, DO_STAGE, VMK) do {                               \
    if ((VMK) == 6)                                                     \
        asm volatile("s_waitcnt vmcnt(6) lgkmcnt(0)" ::: "memory");     \
    else                                                                \
        asm volatile("s_waitcnt vmcnt(0) lgkmcnt(0)" ::: "memory");     \
    __builtin_amdgcn_s_barrier();                                       \
    if (DO_STAGE) GSTAGE(ST);                                           \
    bf16x8 af0 = *(const bf16x8*)(smem + (RD) + abase + 0 * 1024);      \
    bf16x8 af1 = *(const bf16x8*)(smem + (RD) + abase + 1 * 1024);      \
    bf16x8 af2 = *(const bf16x8*)(smem + (RD) + abase + 2 * 1024);      \
    bf16x8 af3 = *(const bf16x8*)(smem + (RD) + abase + 3 * 1024);      \
    bf16x8 af4 = *(const bf16x8*)(smem + (RD) + abase + 4 * 1024);      \
    bf16x8 af5 = *(const bf16x8*)(smem + (RD) + abase + 5 * 1024);      \
    bf16x8 af6 = *(const bf16x8*)(smem + (RD) + abase + 6 * 1024);      \
    bf16x8 af7 = *(const bf16x8*)(smem + (RD) + abase + 7 * 1024);      \
    bf16x8 bq0 = *(const bf16x8*)(smem + (RD) + bbase + 0 * 1024);      \
    bf16x8 bq1 = *(const bf16x8*)(smem + (RD) + bbase + 1 * 1024);      \
    bf16x8 bq2 = *(const bf16x8*)(smem + (RD) + bbase + 2 * 1024);      \
    bf16x8 bq3 = *(const bf16x8*)(smem + (RD) + bbase + 3 * 1024);      \
    GM4(0, af0); GM4(1, af1); GM4(2, af2); GM4(3, af3);                 \
    GM4(4, af4); GM4(5, af5); GM4(6, af6); GM4(7, af7);                 \
} while (0)

template <int MODE>
__global__ __launch_bounds__(256, 2)
void gemm_bt(const __bf16* __restrict__ A, int lda,
             const __bf16* __restrict__ Bt,
             const void* __restrict__ bias,
             void* __restrict__ Cout, int ldc,
             int K, const int* __restrict__ flag,
             __bf16* __restrict__ vt) {
    __shared__ __align__(16) char smem[73728];
    const int tid  = threadIdx.x;
    const int wid  = tid >> 6;
    const int lane = tid & 63;
    const int quad = lane >> 4;
    const int l15  = lane & 15;

    // identity tile mapping, M-fast
    const int bm = blockIdx.x * 256;
    const int bn = blockIdx.y * 128;

    const int wm = (wid & 1) * 128;   // M half of 256
    const int wn = (wid >> 1) * 64;   // N half of 128
    const int srow  = lane >> 2;
    const int sslot = lane & 3;

    // staging: pre-swizzled global col chunk (same for all rows: base mult of 16)
    const int cchunk = ((sslot ^ ((srow >> 1) & 3)) << 3);
    // A: wave wid covers rows [wid*64, wid*64+64), 4 async16 (16 rows each)
    const __bf16* gA0 = A + (size_t)(bm + wid * 64 +  0 + srow) * lda + cchunk;
    const __bf16* gA1 = A + (size_t)(bm + wid * 64 + 16 + srow) * lda + cchunk;
    const __bf16* gA2 = A + (size_t)(bm + wid * 64 + 32 + srow) * lda + cchunk;
    const __bf16* gA3 = A + (size_t)(bm + wid * 64 + 48 + srow) * lda + cchunk;
    // B: wave wid covers rows [wid*32, wid*32+32), 2 async16
    const __bf16* gB0 = Bt + (size_t)(bn + wid * 32 +  0 + srow) * K + cchunk;
    const __bf16* gB1 = Bt + (size_t)(bn + wid * 32 + 16 + srow) * K + cchunk;
    const int stA = wid * 4096;   // byte offset of wave's A stage region
    const int stB = wid * 2048;   // byte offset within B region

    // frag read bases (swizzle slot is mi/ni-invariant: (rf>>1)&3 == (l15>>1)&3)
    const int sl = (quad ^ ((l15 >> 1) & 3)) * 16;
    const int abase = (wm + l15) * 64 + sl;            // + mi*1024
    const int bbase = 16384 + (wn + l15) * 64 + sl;    // + ni*1024

    f32x4 acc[8][4];
#pragma unroll
    for (int i = 0; i < 8; ++i)
#pragma unroll
        for (int j = 0; j < 4; ++j) acc[i][j] = (f32x4)0.0f;

    // ---- prologue: stage tile 0 -> buf0, tile 1 -> buf1 (12 loads in flight)
    GSTAGE(0);
    GSTAGE(24576);

    // ---- main loop: 24 tiles = 7 literal groups of 3 + 3-tile tail ----
#pragma unroll 1
    for (int g = 0; g < 7; ++g) {
        GTILE(0,     49152, true, 6);   // tile 3g+0: read buf0, stage -> buf2
        GTILE(24576, 0,     true, 6);   // tile 3g+1: read buf1, stage -> buf0
        GTILE(49152, 24576, true, 6);   // tile 3g+2: read buf2, stage -> buf1
    }
    GTILE(0,     49152, true,  6);      // tile 21: stages tile 23 -> buf2
    GTILE(24576, 0,     false, 6);      // tile 22
    GTILE(49152, 0,     false, 0);      // tile 23: final drain

    // ---- MODE 0 V-range blocks: write acc transposed to Vt, skip Cout ----
    if (MODE == 0 && bn >= 1536) {
        const int bq = bm >> 10;                         // batch index
        const int n0 = (bm & 1023) + wm + quad * 4;      // n base for this lane
        const int colb = bn - 1536 + wn;                 // V feature base
        // vt row = b*768 + col
#pragma unroll
        for (int mi = 0; mi < 8; ++mi)
#pragma unroll
            for (int ni = 0; ni < 4; ++ni) {
                int col = colb + ni * 16 + l15;
                bf16x4 v;
                v[0] = (__bf16)acc[mi][ni][0];
                v[1] = (__bf16)acc[mi][ni][1];
                v[2] = (__bf16)acc[mi][ni][2];
                v[3] = (__bf16)acc[mi][ni][3];
                *(bf16x4*)&vt[((size_t)bq * 768 + col) * 1024 + n0 + mi * 16] = v;
            }
        return;   // block-uniform branch
    }

    // ---- epilogue: bias add in-register, then LDS-staged coalesced stores ----
    const int f = (MODE == 1) ? *flag : 0;
    if (MODE == 1) {
#pragma unroll
        for (int ni = 0; ni < 4; ++ni) {
            int col = bn + wn + ni * 16 + l15;
            float bv = f ? ((const float*)bias)[col] : (float)((const __bf16*)bias)[col];
#pragma unroll
            for (int mi = 0; mi < 8; ++mi)
#pragma unroll
                for (int rg = 0; rg < 4; ++rg) acc[mi][ni][rg] += bv;
        }
    }

    if (MODE == 0 || !f) {
        // bf16 output: 8 chunks of 32 rows; cs = [32][136] bf16 (8704 B)
        __bf16* cs = (__bf16*)smem;
#pragma unroll
        for (int c = 0; c < 8; ++c) {
            __syncthreads();
            if (wm == (c >> 2) * 128) {
#pragma unroll
                for (int mloc = 0; mloc < 2; ++mloc) {
#pragma unroll
                    for (int ni = 0; ni < 4; ++ni) {
                        int col = wn + ni * 16 + l15;
#pragma unroll
                        for (int rg = 0; rg < 4; ++rg)
                            cs[(mloc * 16 + quad * 4 + rg) * 136 + col] =
                                (__bf16)acc[(c & 3) * 2 + mloc][ni][rg];
                    }
                }
            }
            __syncthreads();
#pragma unroll
            for (int p = 0; p < 2; ++p) {
                int row  = p * 16 + (tid >> 4);
                int colc = tid & 15;
                bf16x8 v = *(const bf16x8*)&cs[row * 136 + colc * 8];
                *(bf16x8*)((__bf16*)Cout + (size_t)(bm + c * 32 + row) * ldc + bn + colc * 8) = v;
            }
        }
    } else {
        // fp32 output: 16 chunks of 16 rows; cs = [16][132] float (8448 B)
        float* cs = (float*)smem;
#pragma unroll
        for (int c = 0; c < 16; ++c) {
            __syncthreads();
            if (wm == (c >> 3) * 128) {
#pragma unroll
                for (int ni = 0; ni < 4; ++ni) {
                    int col = wn + ni * 16 + l15;
#pragma unroll
                    for (int rg = 0; rg < 4; ++rg)
                        cs[(quad * 4 + rg) * 132 + col] = acc[c & 7][ni][rg];
                }
            }
            __syncthreads();
#pragma unroll
            for (int p = 0; p < 2; ++p) {
                int row  = p * 8 + (tid >> 5);
                int colc = tid & 31;
                float4 v = *(const float4*)&cs[row * 132 + colc * 4];
                *(float4*)((float*)Cout + (size_t)(bm + c * 16 + row) * ldc + bn + colc * 4) = v;
            }
        }
    }
}

// ---------------------------------------------------------------------------
// Flash attention, S^T formulation, async16 staging. Grid (B*H, N/128) --
// bh is blockIdx.x so id%8 = bh%8: all q-tiles of a head pin to one XCD.
// R15/R18 configuration: K/V double-buffered; per-kt wait vmcnt(0)+lgkmcnt(0)
// (WAR fence) + s_barrier; stage(kt+1) issued right after the barrier.
// LDS: K buf k @ k*8192; V buf k @ 16384 + k*8192; Ps @ 32768 (55296 total).
// ---------------------------------------------------------------------------
__global__ __launch_bounds__(256, 2)
void attn(const __bf16* qkv, const __bf16* __restrict__ vt,
          const int* __restrict__ perm, __bf16* O, int ldo) {
    __shared__ __align__(16) char smem[55296];
    __bf16* Qs = (__bf16*)smem;              // 128 x 64 (dies after qf loaded)
    __bf16* Ps = (__bf16*)(smem + 32768);    // 4 waves x [32 x 88]

    const int tid  = threadIdx.x;
    const int wid  = tid >> 6;
    const int lane = tid & 63;
    const int quad = lane >> 4;
    const int l15  = lane & 15;
    const int bh = blockIdx.x;
    const int q0 = blockIdx.y * 128;
    const int b = bh / 12, h = bh % 12;
    const size_t row_base = (size_t)b * 1024;
    const int qcol = h * 64;
    const int kcol = 768 + h * 64;
    const int srow8  = lane >> 3;
    const int sslot8 = lane & 7;
    __bf16* Pw = Ps + wid * (32 * 88);

    // ---- stage Q (perm-gathered rows) ----
#pragma unroll
    for (int is = 0; is < 4; ++is) {
        int r = is * 32 + wid * 8 + srow8;
        int gr = perm[q0 + r];
        int chunk = sslot8 ^ (r & 7);
        async16(qkv + (row_base + gr) * 2304 + qcol + chunk * 8,
                &Qs[(is * 32 + wid * 8) * 64]);
    }
    __syncthreads();

    bf16x8 qf[2][2];
#pragma unroll
    for (int mi = 0; mi < 2; ++mi) {
        int r = wid * 32 + mi * 16 + l15;
#pragma unroll
        for (int ks = 0; ks < 2; ++ks)
            qf[mi][ks] = *(const bf16x8*)&Qs[r * 64 + (((ks * 4 + quad) ^ (r & 7)) * 8)];
    }
    // my qf reads must complete before staging overwrites the Qs region
    asm volatile("s_waitcnt lgkmcnt(0)" ::: "memory");
    __builtin_amdgcn_sched_barrier(0);
    __builtin_amdgcn_s_barrier();

    // ---- loop-invariant LDS element offsets ----
    const int off0 = l15 * 64 + (((0 * 4 + quad) ^ (l15 & 7)) * 8); // ks/ks2 = 0
    const int off1 = l15 * 64 + (((1 * 4 + quad) ^ (l15 & 7)) * 8); // ks/ks2 = 1
    const int pwb  = l15 * 88 + quad * 4;   // + mi*1408 + ki*16 (immediates)
    const int pfb  = l15 * 88 + quad * 8;   // + mi*1408 + ks2*32 (immediates)

    // ---- held global staging pointers (incremented per stage) ----
    const int rK = wid * 8 + srow8;                 // +32 for second chunk
    const int ck = sslot8 ^ (rK & 7);               // (is*32)&7 == 0
    const __bf16* kg0 = qkv + (row_base + rK) * 2304 + kcol + ck * 8;
    const __bf16* kg1 = kg0 + (size_t)32 * 2304;
    const __bf16* vg0 = vt + ((size_t)bh * 64 + rK) * 1024 + ck * 8;
    const __bf16* vg1 = vg0 + (size_t)32 * 1024;

    f32x4 acco[2][4];
#pragma unroll
    for (int mi = 0; mi < 2; ++mi)
#pragma unroll
        for (int ni = 0; ni < 4; ++ni) acco[mi][ni] = (f32x4)0.0f;
    float lsum[2] = {0.0f, 0.0f};

    const float cfac = 0.125f * 1.44269504088896340736f;

    // stage into buf kb: K @ kb*8192, V @ 16384 + kb*8192
#define ASTAGE(KB, VB) do {                                             \
        async16(kg0, smem + (KB) + wid * 1024);                         \
        async16(kg1, smem + (KB) + 4096 + wid * 1024);                  \
        async16(vg0, smem + (VB) + wid * 1024);                         \
        async16(vg1, smem + (VB) + 4096 + wid * 1024);                  \
        kg0 += (size_t)64 * 2304; kg1 += (size_t)64 * 2304;             \
        vg0 += 64; vg1 += 64;                                           \
    } while (0)

    auto compute = [&](const __bf16* Kb, const __bf16* Vb) {
#pragma unroll
        for (int half = 0; half < 2; ++half) {
            // ---- QK^T for ki = half*2 .. half*2+1 ----
            f32x4 accs[2][2];
#pragma unroll
            for (int ki = 0; ki < 2; ++ki)
#pragma unroll
                for (int mi = 0; mi < 2; ++mi) accs[ki][mi] = (f32x4)0.0f;
#pragma unroll
            for (int ks = 0; ks < 2; ++ks) {
                const int off = ks ? off1 : off0;
                bf16x8 kf0 = *(const bf16x8*)&Kb[(half * 2 + 0) * 1024 + off];
                bf16x8 kf1 = *(const bf16x8*)&Kb[(half * 2 + 1) * 1024 + off];
                accs[0][0] = mfma16(kf0, qf[0][ks], accs[0][0]);
                accs[0][1] = mfma16(kf0, qf[1][ks], accs[0][1]);
                accs[1][0] = mfma16(kf1, qf[0][ks], accs[1][0]);
                accs[1][1] = mfma16(kf1, qf[1][ks], accs[1][1]);
            }

            // ---- softmax (static bias -8; cancels in normalization) ----
#pragma unroll
            for (int ki = 0; ki < 2; ++ki)
#pragma unroll
                for (int mi = 0; mi < 2; ++mi) {
                    bf16x4 pk;
                    float s0 = __builtin_amdgcn_exp2f(accs[ki][mi][0] * cfac - 8.0f);
                    float s1 = __builtin_amdgcn_exp2f(accs[ki][mi][1] * cfac - 8.0f);
                    float s2 = __builtin_amdgcn_exp2f(accs[ki][mi][2] * cfac - 8.0f);
                    float s3 = __builtin_amdgcn_exp2f(accs[ki][mi][3] * cfac - 8.0f);
                    pk[0] = (__bf16)s0; pk[1] = (__bf16)s1;
                    pk[2] = (__bf16)s2; pk[3] = (__bf16)s3;
                    lsum[mi] += (s0 + s1) + (s2 + s3);
                    *(bf16x4*)&Pw[pwb + mi * 1408 + (half * 2 + ki) * 16] = pk;
                }

            // ---- PV for ks2 = half (same-wave LDS RAW; lgkmcnt orders it) ----
            {
                bf16x8 pf0 = *(const bf16x8*)&Pw[pfb + 0 * 1408 + half * 32];
                bf16x8 pf1 = *(const bf16x8*)&Pw[pfb + 1 * 1408 + half * 32];
                const int offv = half ? off1 : off0;
#pragma unroll
                for (int ni = 0; ni < 4; ++ni) {
                    bf16x8 vf = *(const bf16x8*)&Vb[ni * 1024 + offv];
                    acco[0][ni] = mfma16(pf0, vf, acco[0][ni]);
                    acco[1][ni] = mfma16(pf1, vf, acco[1][ni]);
                }
            }
        }
    };

    // ---- prologue: stage kt=0 into buf0 ----
    ASTAGE(0, 16384);

    // ---- main loop: 16 kt, unrolled x2 for literal buffer offsets ----
#pragma unroll 1
    for (int kt2 = 0; kt2 < 8; ++kt2) {
        asm volatile("s_waitcnt vmcnt(0) lgkmcnt(0)" ::: "memory");
        __builtin_amdgcn_s_barrier();
        ASTAGE(8192, 16384 + 8192);
        compute((const __bf16*)smem, (const __bf16*)(smem + 16384));
        asm volatile("s_waitcnt vmcnt(0) lgkmcnt(0)" ::: "memory");
        __builtin_amdgcn_s_barrier();
        if (kt2 < 7) ASTAGE(0, 16384);
        compute((const __bf16*)(smem + 8192), (const __bf16*)(smem + 16384 + 8192));
    }
#undef ASTAGE

#pragma unroll
    for (int off = 16; off < 64; off <<= 1) {
        lsum[0] += __shfl_xor(lsum[0], off, 64);
        lsum[1] += __shfl_xor(lsum[1], off, 64);
    }

#pragma unroll
    for (int mi = 0; mi < 2; ++mi) {
#pragma unroll
        for (int rg = 0; rg < 4; ++rg) {
            float inv = 1.0f / __shfl(lsum[mi], quad * 4 + rg, 64);
            int orow = q0 + wid * 32 + mi * 16 + quad * 4 + rg;
#pragma unroll
            for (int ni = 0; ni < 4; ++ni) {
                int ocol = h * 64 + ni * 16 + l15;
                O[(row_base + orow) * (size_t)ldo + ocol] = (__bf16)(acco[mi][ni][rg] * inv);
            }
        }
    }
}

// ---------------------------------------------------------------------------
// Workspace layout (bytes), total ~130.5 MB (see round-3 comment).
// ---------------------------------------------------------------------------
extern "C" void kernel_launch(void* const* d_in, const int* in_sizes, int n_in,
                              void* d_out, int out_size, void* d_ws, size_t ws_size,
                              hipStream_t stream) {
    (void)in_sizes; (void)n_in; (void)out_size; (void)ws_size;
    const void* x_raw    = d_in[0];
    const void* Wqkv_raw = d_in[1];
    const void* Wout_raw = d_in[2];
    const void* bout_raw = d_in[3];
    const int*  perm     = (const int*)d_in[4];

    char* ws = (char*)d_ws;
    int*    flag = (int*)ws;
    __bf16* Xc   = (__bf16*)(ws + 256);
    __bf16* QKV  = (__bf16*)(ws + 25166080);
    __bf16* Vt   = (__bf16*)(ws + 100663552);
    __bf16* Wqt  = (__bf16*)(ws + 125829376);
    __bf16* Wot  = (__bf16*)(ws + 129368320);
    __bf16* Obuf = QKV + 1536; // O[n][768] in QKV's V columns, ld 2304

    prep<<<1600, 256, 0, stream>>>(x_raw, Xc, Wqkv_raw, Wqt, Wout_raw, Wot, flag);
    gemm_bt<0><<<dim3(64, 18), 256, 0, stream>>>(Xc, 768, Wqt, nullptr, QKV, 2304, 768, nullptr, Vt);
    attn<<<dim3(192, 8), 256, 0, stream>>>(QKV, Vt, perm, Obuf, 2304);
    gemm_bt<1><<<dim3(64, 6), 256, 0, stream>>>(Obuf, 2304, Wot, bout_raw, d_out, 768, 768, flag, nullptr);
}